// Round 1
// baseline (644.475 us; speedup 1.0000x reference)
//
#include <hip/hip_runtime.h>
#include <hip/hip_bf16.h>

#define BB 8
#define CC 128
#define CPj 16
#define NN 4096

typedef __attribute__((ext_vector_type(4))) float f32x4;
typedef __attribute__((ext_vector_type(4))) short s16x4;
typedef __attribute__((ext_vector_type(8))) short s16x8;

__device__ inline short f2bf(float f){
  unsigned u = __float_as_uint(f);
  u += 0x7FFFu + ((u >> 16) & 1u);
  return (short)(u >> 16);
}

// ---------------- K1: fused 1x1-conv projections -> bf16 f/g/h ----------------
// grid: B * (N/64) * 4 co-groups; block 256. LDS-stages x tile [128c][64n].
__global__ __launch_bounds__(256) void k_proj(
    const float* __restrict__ x,  const float* __restrict__ Wf, const float* __restrict__ bf,
    const float* __restrict__ Wg, const float* __restrict__ bg,
    const float* __restrict__ Wh, const float* __restrict__ bh,
    short* __restrict__ fT, short* __restrict__ gT, short* __restrict__ hL)
{
  __shared__ float xt[128][64];
  const int blk   = blockIdx.x;
  const int cog   = blk & 3;
  const int ntile = (blk >> 2) & 63;
  const int b     = blk >> 8;
  const int n0    = ntile * 64;
  const int tid   = threadIdx.x;

  for (int idx = tid; idx < 128*64; idx += 256){
    int c = idx >> 6, j = idx & 63;
    xt[c][j] = x[((size_t)(b*128 + c))*NN + n0 + j];
  }
  __syncthreads();

  const int nl  = tid & 63;
  const int sub = __builtin_amdgcn_readfirstlane(tid >> 6);  // wave-uniform
  const int cobase = cog*40 + sub*10;                        // 16 groups of 10 over 160 out-ch

  const float* wr[10]; float bias[10];
  #pragma unroll
  for (int i=0;i<10;++i){
    int co = cobase + i;
    if (co < 16)      { wr[i] = Wf + co*128;      bias[i] = bf[co];    }
    else if (co < 32) { wr[i] = Wg + (co-16)*128; bias[i] = bg[co-16]; }
    else              { wr[i] = Wh + (co-32)*128; bias[i] = bh[co-32]; }
  }

  float acc[10];
  #pragma unroll
  for (int i=0;i<10;++i) acc[i] = 0.f;

  for (int c=0;c<128;++c){
    float xv = xt[c][nl];
    #pragma unroll
    for (int i=0;i<10;++i) acc[i] += wr[i][c]*xv;
  }

  const int n = n0 + nl;
  #pragma unroll
  for (int i=0;i<10;++i){
    int co = cobase + i;
    short v = f2bf(acc[i] + bias[i]);
    if (co < 16)      fT[((size_t)b*NN + n)*CPj + co]        = v;
    else if (co < 32) gT[((size_t)b*NN + n)*CPj + (co-16)]   = v;
    else              hL[((size_t)(b*CC + (co-32)))*NN + n]  = v;
  }
}

// ---------------- K2: per-row softmax stats M[n], 1/Z[n] ----------------
// grid: B * (N/64); block 256 = 4 waves; wave owns 16 n-rows, loops m in 16-chunks.
__global__ __launch_bounds__(256) void k_stats(
    const short* __restrict__ fT, const short* __restrict__ gT,
    float* __restrict__ Mrow, float* __restrict__ Zinv)
{
  const int blk = blockIdx.x;
  const int b = blk >> 6, ntile = blk & 63;
  const int tid = threadIdx.x;
  const int w = tid >> 6, l = tid & 63;
  const int g = l >> 4, lm = l & 15;
  const int n0w = ntile*64 + w*16;
  const f32x4 zero4 = {0.f,0.f,0.f,0.f};

  s16x4 f4 = *(const s16x4*)(fT + ((size_t)b*NN + n0w + lm)*CPj + 4*g);
  s16x8 fa = {f4[0],f4[1],f4[2],f4[3],0,0,0,0};

  float rm[4], rs[4];
  #pragma unroll
  for (int i=0;i<4;++i){ rm[i] = -3.0e38f; rs[i] = 0.f; }

  for (int m0=0; m0<NN; m0+=16){
    s16x4 g4 = *(const s16x4*)(gT + ((size_t)b*NN + m0 + lm)*CPj + 4*g);
    s16x8 gb = {g4[0],g4[1],g4[2],g4[3],0,0,0,0};
    f32x4 d = __builtin_amdgcn_mfma_f32_16x16x32_bf16(fa, gb, zero4, 0,0,0);
    #pragma unroll
    for (int i=0;i<4;++i){
      float v  = d[i];
      float nm = fmaxf(rm[i], v);
      rs[i] = rs[i]*__expf(rm[i]-nm) + __expf(v-nm);
      rm[i] = nm;
    }
  }
  // reduce over the 16 lanes (lm) sharing the same 4 rows
  #pragma unroll
  for (int i=0;i<4;++i){
    #pragma unroll
    for (int mask=1; mask<16; mask<<=1){
      float om = __shfl_xor(rm[i], mask);
      float os = __shfl_xor(rs[i], mask);
      float nm = fmaxf(rm[i], om);
      rs[i] = rs[i]*__expf(rm[i]-nm) + os*__expf(om-nm);
      rm[i] = nm;
    }
  }
  if (lm == 0){
    #pragma unroll
    for (int i=0;i<4;++i){
      int n = n0w + 4*g + i;
      Mrow[(size_t)b*NN + n] = rm[i];
      Zinv[(size_t)b*NN + n] = 1.0f / rs[i];
    }
  }
}

// ---------------- K3: recompute S, P = exp(S-M)/Z, out = x + gamma * P^T h ----------------
// grid: B * (N/64) m-tiles; block 256 = 4 waves; wave owns 16 m, all 128 c; loops n in 32-chunks.
__global__ __launch_bounds__(256) void k_attend(
    const float* __restrict__ x, const short* __restrict__ fT, const short* __restrict__ gT,
    const short* __restrict__ hL, const float* __restrict__ Mrow, const float* __restrict__ Zinv,
    const float* __restrict__ gamma, float* __restrict__ out)
{
  const int blk = blockIdx.x;
  const int b = blk >> 6, mtile = blk & 63;
  const int tid = threadIdx.x;
  const int w = tid >> 6, l = tid & 63;
  const int g = l >> 4, lm = l & 15;
  const int m0 = mtile*64 + w*16;
  const f32x4 zero4 = {0.f,0.f,0.f,0.f};

  // B-operand of S-mfma: g rows for this wave's 16 m (loop-invariant)
  s16x4 g4 = *(const s16x4*)(gT + ((size_t)b*NN + m0 + lm)*CPj + 4*g);
  s16x8 gb = {g4[0],g4[1],g4[2],g4[3],0,0,0,0};

  f32x4 acc[8];
  #pragma unroll
  for (int cs=0;cs<8;++cs) acc[cs] = zero4;

  for (int nb=0; nb<NN; nb+=32){
    // two 16-n S tiles: D lane = S[nb(+16) + 4g + reg][m0 + lm]
    s16x4 fa4 = *(const s16x4*)(fT + ((size_t)b*NN + nb      + lm)*CPj + 4*g);
    s16x4 fb4 = *(const s16x4*)(fT + ((size_t)b*NN + nb + 16 + lm)*CPj + 4*g);
    s16x8 fa0 = {fa4[0],fa4[1],fa4[2],fa4[3],0,0,0,0};
    s16x8 fa1 = {fb4[0],fb4[1],fb4[2],fb4[3],0,0,0,0};
    f32x4 d0 = __builtin_amdgcn_mfma_f32_16x16x32_bf16(fa0, gb, zero4, 0,0,0);
    f32x4 d1 = __builtin_amdgcn_mfma_f32_16x16x32_bf16(fa1, gb, zero4, 0,0,0);

    f32x4 M0 = *(const f32x4*)(Mrow + (size_t)b*NN + nb      + 4*g);
    f32x4 M1 = *(const f32x4*)(Mrow + (size_t)b*NN + nb + 16 + 4*g);
    f32x4 Z0 = *(const f32x4*)(Zinv + (size_t)b*NN + nb      + 4*g);
    f32x4 Z1 = *(const f32x4*)(Zinv + (size_t)b*NN + nb + 16 + 4*g);

    // P^T fragment: elems 0-3 <- n=nb+4g+i, elems 4-7 <- n=nb+16+4g+i (same k-map as hb below)
    s16x8 af;
    #pragma unroll
    for (int i=0;i<4;++i){
      af[i]   = f2bf(__expf(d0[i]-M0[i]) * Z0[i]);
      af[4+i] = f2bf(__expf(d1[i]-M1[i]) * Z1[i]);
    }

    #pragma unroll
    for (int cs=0;cs<8;++cs){
      int c = cs*16 + lm;
      const short* hp = hL + ((size_t)(b*CC + c))*NN + nb + 4*g;
      s16x4 lo = *(const s16x4*)(hp);
      s16x4 hi = *(const s16x4*)(hp + 16);
      s16x8 hb = {lo[0],lo[1],lo[2],lo[3],hi[0],hi[1],hi[2],hi[3]};
      acc[cs] = __builtin_amdgcn_mfma_f32_16x16x32_bf16(af, hb, acc[cs], 0,0,0);
    }
  }

  const float gm = gamma[0];
  #pragma unroll
  for (int cs=0;cs<8;++cs){
    int c = cs*16 + lm;
    size_t base = ((size_t)(b*CC + c))*NN + m0 + 4*g;   // acc[cs][i] -> m = m0+4g+i
    f32x4 xv = *(const f32x4*)(x + base);
    f32x4 ov;
    #pragma unroll
    for (int i=0;i<4;++i) ov[i] = xv[i] + gm*acc[cs][i];
    *(f32x4*)(out + base) = ov;
  }
}

extern "C" void kernel_launch(void* const* d_in, const int* in_sizes, int n_in,
                              void* d_out, int out_size, void* d_ws, size_t ws_size,
                              hipStream_t stream)
{
  const float* x     = (const float*)d_in[0];
  const float* Wf    = (const float*)d_in[1];
  const float* bf    = (const float*)d_in[2];
  const float* Wg    = (const float*)d_in[3];
  const float* bg    = (const float*)d_in[4];
  const float* Wh    = (const float*)d_in[5];
  const float* bh    = (const float*)d_in[6];
  const float* gamma = (const float*)d_in[7];
  float* out = (float*)d_out;

  short* fT   = (short*)d_ws;                       // [B][N][16] bf16
  short* gT   = fT + (size_t)BB*NN*CPj;             // [B][N][16] bf16
  short* hL   = gT + (size_t)BB*NN*CPj;             // [B][C][N]  bf16
  float* Mrow = (float*)(hL + (size_t)BB*CC*NN);    // [B][N]
  float* Zinv = Mrow + (size_t)BB*NN;               // [B][N]

  k_proj  <<<BB*64*4, 256, 0, stream>>>(x, Wf, bf, Wg, bg, Wh, bh, fT, gT, hL);
  k_stats <<<BB*64,   256, 0, stream>>>(fT, gT, Mrow, Zinv);
  k_attend<<<BB*64,   256, 0, stream>>>(x, fT, gT, hL, Mrow, Zinv, gamma, out);
}

// Round 2
// 174.900 us; speedup vs baseline: 3.6848x; 3.6848x over previous
//
#include <hip/hip_runtime.h>
#include <hip/hip_bf16.h>

#define BB 8
#define CC 128
#define CPj 16
#define NN 4096

typedef __attribute__((ext_vector_type(4))) float f32x4;
typedef __attribute__((ext_vector_type(4))) short s16x4;
typedef __attribute__((ext_vector_type(8))) short s16x8;

__device__ inline short f2bf(float f){
  unsigned u = __float_as_uint(f);
  u += 0x7FFFu + ((u >> 16) & 1u);
  return (short)(u >> 16);
}

// ---------------- K1: fused 1x1-conv projections -> bf16 f/g/h ----------------
__global__ __launch_bounds__(256) void k_proj(
    const float* __restrict__ x,  const float* __restrict__ Wf, const float* __restrict__ bf,
    const float* __restrict__ Wg, const float* __restrict__ bg,
    const float* __restrict__ Wh, const float* __restrict__ bh,
    short* __restrict__ fT, short* __restrict__ gT, short* __restrict__ hL)
{
  __shared__ float xt[128][64];
  const int blk   = blockIdx.x;
  const int cog   = blk & 3;
  const int ntile = (blk >> 2) & 63;
  const int b     = blk >> 8;
  const int n0    = ntile * 64;
  const int tid   = threadIdx.x;

  for (int idx = tid; idx < 128*64; idx += 256){
    int c = idx >> 6, j = idx & 63;
    xt[c][j] = x[((size_t)(b*128 + c))*NN + n0 + j];
  }
  __syncthreads();

  const int nl  = tid & 63;
  const int sub = __builtin_amdgcn_readfirstlane(tid >> 6);
  const int cobase = cog*40 + sub*10;

  const float* wr[10]; float bias[10];
  #pragma unroll
  for (int i=0;i<10;++i){
    int co = cobase + i;
    if (co < 16)      { wr[i] = Wf + co*128;      bias[i] = bf[co];    }
    else if (co < 32) { wr[i] = Wg + (co-16)*128; bias[i] = bg[co-16]; }
    else              { wr[i] = Wh + (co-32)*128; bias[i] = bh[co-32]; }
  }

  float acc[10];
  #pragma unroll
  for (int i=0;i<10;++i) acc[i] = 0.f;

  for (int c=0;c<128;++c){
    float xv = xt[c][nl];
    #pragma unroll
    for (int i=0;i<10;++i) acc[i] += wr[i][c]*xv;
  }

  const int n = n0 + nl;
  #pragma unroll
  for (int i=0;i<10;++i){
    int co = cobase + i;
    short v = f2bf(acc[i] + bias[i]);
    if (co < 16)      fT[((size_t)b*NN + n)*CPj + co]        = v;
    else if (co < 32) gT[((size_t)b*NN + n)*CPj + (co-16)]   = v;
    else              hL[((size_t)(b*CC + (co-32)))*NN + n]  = v;
  }
}

// ---------------- K2: per-row softmax stats M[n], 1/Z[n] ----------------
// block 512 = 8 waves: 4 n-slices x 2 m-halves; m unrolled x2; LDS merge.
__global__ __launch_bounds__(512,4) void k_stats(
    const short* __restrict__ fT, const short* __restrict__ gT,
    float* __restrict__ Mrow, float* __restrict__ Zinv)
{
  __shared__ float sm[4][16], ss[4][16];
  const int blk = blockIdx.x;
  const int b = blk >> 6, ntile = blk & 63;
  const int tid = threadIdx.x;
  const int w = tid >> 6, l = tid & 63;
  const int g = l >> 4, lm = l & 15;
  const int s = w & 3, mh = w >> 2;
  const int n0w = ntile*64 + s*16;
  const int mbase = mh*2048;
  const f32x4 zero4 = {0.f,0.f,0.f,0.f};

  s16x4 f4 = *(const s16x4*)(fT + ((size_t)b*NN + n0w + lm)*CPj + 4*g);
  s16x8 fa = {f4[0],f4[1],f4[2],f4[3],0,0,0,0};

  float rm[4], rs[4];
  #pragma unroll
  for (int i=0;i<4;++i){ rm[i] = -3.0e38f; rs[i] = 0.f; }

  for (int m0 = mbase; m0 < mbase + 2048; m0 += 32){
    s16x4 ga = *(const s16x4*)(gT + ((size_t)b*NN + m0      + lm)*CPj + 4*g);
    s16x4 gc = *(const s16x4*)(gT + ((size_t)b*NN + m0 + 16 + lm)*CPj + 4*g);
    s16x8 gA = {ga[0],ga[1],ga[2],ga[3],0,0,0,0};
    s16x8 gB = {gc[0],gc[1],gc[2],gc[3],0,0,0,0};
    f32x4 d0 = __builtin_amdgcn_mfma_f32_16x16x32_bf16(fa, gA, zero4, 0,0,0);
    f32x4 d1 = __builtin_amdgcn_mfma_f32_16x16x32_bf16(fa, gB, zero4, 0,0,0);
    #pragma unroll
    for (int i=0;i<4;++i){
      float nm = fmaxf(fmaxf(rm[i], d0[i]), d1[i]);
      rs[i] = rs[i]*__expf(rm[i]-nm) + __expf(d0[i]-nm) + __expf(d1[i]-nm);
      rm[i] = nm;
    }
  }
  // reduce over 16 lm lanes sharing rows
  #pragma unroll
  for (int i=0;i<4;++i){
    #pragma unroll
    for (int mask=1; mask<16; mask<<=1){
      float om = __shfl_xor(rm[i], mask);
      float os = __shfl_xor(rs[i], mask);
      float nm = fmaxf(rm[i], om);
      rs[i] = rs[i]*__expf(rm[i]-nm) + os*__expf(om-nm);
      rm[i] = nm;
    }
  }
  if (mh == 1 && lm == 0){
    #pragma unroll
    for (int i=0;i<4;++i){ sm[s][4*g+i] = rm[i]; ss[s][4*g+i] = rs[i]; }
  }
  __syncthreads();
  if (mh == 0 && lm == 0){
    #pragma unroll
    for (int i=0;i<4;++i){
      float om = sm[s][4*g+i], os = ss[s][4*g+i];
      float nm = fmaxf(rm[i], om);
      float z  = rs[i]*__expf(rm[i]-nm) + os*__expf(om-nm);
      int n = n0w + 4*g + i;
      Mrow[(size_t)b*NN + n] = nm;
      Zinv[(size_t)b*NN + n] = 1.0f / z;
    }
  }
}

// ---------------- K3: out = x + gamma * P^T h ----------------
// block 512 = 8 waves: 4 m-waves x 2 n-halves. LDS-staged h tiles (T14 split),
// register prefetch of f/M/Z, cross-half LDS reduction.
__global__ __launch_bounds__(512,4) void k_attend(
    const float* __restrict__ x, const short* __restrict__ fT, const short* __restrict__ gT,
    const short* __restrict__ hL, const float* __restrict__ Mrow, const float* __restrict__ Zinv,
    const float* __restrict__ gamma, float* __restrict__ out)
{
  __shared__ __align__(16) char lds_raw[32768];
  short (*ht)[128][40] = (short (*)[128][40])lds_raw;   // [half][c][32 + 8 pad]
  f32x4 (*red)[64][8]  = (f32x4 (*)[64][8])lds_raw;     // overlay, used after loop

  const int blk = blockIdx.x;
  const int b = blk >> 6, mtile = blk & 63;
  const int tid = threadIdx.x;
  const int w = tid >> 6, l = tid & 63;
  const int g = l >> 4, lm = l & 15;
  const int mw = w & 3, nh = w >> 2;
  const int m0 = mtile*64 + mw*16;
  const int nbase = nh*2048;

  const int qid  = mw*64 + l;          // 0..255 within this n-half
  const int sc   = qid >> 2;           // c row 0..63 (+64 second)
  const int scol = (qid & 3)*8;        // short col 0,8,16,24

  const size_t hrow0 = ((size_t)(b*CC + sc))*NN;
  const size_t hrow1 = ((size_t)(b*CC + sc + 64))*NN;

  const f32x4 zero4 = {0.f,0.f,0.f,0.f};

  s16x4 g4 = *(const s16x4*)(gT + ((size_t)b*NN + m0 + lm)*CPj + 4*g);
  s16x8 gb = {g4[0],g4[1],g4[2],g4[3],0,0,0,0};

  f32x4 acc[8];
  #pragma unroll
  for (int cs=0;cs<8;++cs) acc[cs] = zero4;

  // prologue: stage chunk 0, prefetch regs for chunk 0
  {
    s16x8 r0 = *(const s16x8*)(hL + hrow0 + nbase + scol);
    s16x8 r1 = *(const s16x8*)(hL + hrow1 + nbase + scol);
    s16x4 r0lo = {r0[0],r0[1],r0[2],r0[3]}, r0hi = {r0[4],r0[5],r0[6],r0[7]};
    s16x4 r1lo = {r1[0],r1[1],r1[2],r1[3]}, r1hi = {r1[4],r1[5],r1[6],r1[7]};
    *(s16x4*)&ht[nh][sc][scol]        = r0lo;
    *(s16x4*)&ht[nh][sc][scol+4]      = r0hi;
    *(s16x4*)&ht[nh][sc+64][scol]     = r1lo;
    *(s16x4*)&ht[nh][sc+64][scol+4]   = r1hi;
  }
  s16x4 fa4 = *(const s16x4*)(fT + ((size_t)b*NN + nbase      + lm)*CPj + 4*g);
  s16x4 fb4 = *(const s16x4*)(fT + ((size_t)b*NN + nbase + 16 + lm)*CPj + 4*g);
  f32x4 M0 = *(const f32x4*)(Mrow + (size_t)b*NN + nbase      + 4*g);
  f32x4 M1 = *(const f32x4*)(Mrow + (size_t)b*NN + nbase + 16 + 4*g);
  f32x4 Z0 = *(const f32x4*)(Zinv + (size_t)b*NN + nbase      + 4*g);
  f32x4 Z1 = *(const f32x4*)(Zinv + (size_t)b*NN + nbase + 16 + 4*g);
  __syncthreads();

  for (int it = 0; it < 64; ++it){
    // T14: issue next chunk's global loads now; write LDS after barrier
    s16x8 r0, r1; s16x4 pfa, pfb; f32x4 pM0,pM1,pZ0,pZ1;
    if (it < 63){
      const int nb2 = nbase + it*32 + 32;
      r0  = *(const s16x8*)(hL + hrow0 + nb2 + scol);
      r1  = *(const s16x8*)(hL + hrow1 + nb2 + scol);
      pfa = *(const s16x4*)(fT + ((size_t)b*NN + nb2      + lm)*CPj + 4*g);
      pfb = *(const s16x4*)(fT + ((size_t)b*NN + nb2 + 16 + lm)*CPj + 4*g);
      pM0 = *(const f32x4*)(Mrow + (size_t)b*NN + nb2      + 4*g);
      pM1 = *(const f32x4*)(Mrow + (size_t)b*NN + nb2 + 16 + 4*g);
      pZ0 = *(const f32x4*)(Zinv + (size_t)b*NN + nb2      + 4*g);
      pZ1 = *(const f32x4*)(Zinv + (size_t)b*NN + nb2 + 16 + 4*g);
    }

    s16x8 fa0 = {fa4[0],fa4[1],fa4[2],fa4[3],0,0,0,0};
    s16x8 fa1 = {fb4[0],fb4[1],fb4[2],fb4[3],0,0,0,0};
    f32x4 d0 = __builtin_amdgcn_mfma_f32_16x16x32_bf16(fa0, gb, zero4, 0,0,0);
    f32x4 d1 = __builtin_amdgcn_mfma_f32_16x16x32_bf16(fa1, gb, zero4, 0,0,0);

    s16x8 af;
    #pragma unroll
    for (int i=0;i<4;++i){
      af[i]   = f2bf(__expf(d0[i]-M0[i]) * Z0[i]);
      af[4+i] = f2bf(__expf(d1[i]-M1[i]) * Z1[i]);
    }

    #pragma unroll
    for (int cs=0;cs<8;++cs){
      const int c = cs*16 + lm;
      s16x4 lo = *(const s16x4*)&ht[nh][c][4*g];
      s16x4 hi = *(const s16x4*)&ht[nh][c][16 + 4*g];
      s16x8 hb = {lo[0],lo[1],lo[2],lo[3],hi[0],hi[1],hi[2],hi[3]};
      acc[cs] = __builtin_amdgcn_mfma_f32_16x16x32_bf16(af, hb, acc[cs], 0,0,0);
    }
    __syncthreads();            // all reads of ht done
    if (it < 63){
      s16x4 r0lo = {r0[0],r0[1],r0[2],r0[3]}, r0hi = {r0[4],r0[5],r0[6],r0[7]};
      s16x4 r1lo = {r1[0],r1[1],r1[2],r1[3]}, r1hi = {r1[4],r1[5],r1[6],r1[7]};
      *(s16x4*)&ht[nh][sc][scol]      = r0lo;
      *(s16x4*)&ht[nh][sc][scol+4]    = r0hi;
      *(s16x4*)&ht[nh][sc+64][scol]   = r1lo;
      *(s16x4*)&ht[nh][sc+64][scol+4] = r1hi;
      fa4 = pfa; fb4 = pfb; M0 = pM0; M1 = pM1; Z0 = pZ0; Z1 = pZ1;
      __syncthreads();          // staging visible
    }
  }

  // cross-half reduction (red overlays ht; all ht reads completed above)
  if (nh == 1){
    #pragma unroll
    for (int cs=0;cs<8;++cs) red[mw][l][cs] = acc[cs];
  }
  __syncthreads();
  if (nh == 0){
    const float gm = gamma[0];
    #pragma unroll
    for (int cs=0;cs<8;++cs){
      f32x4 a = acc[cs] + red[mw][l][cs];
      const int c = cs*16 + lm;
      const size_t base = ((size_t)(b*CC + c))*NN + m0 + 4*g;
      f32x4 xv = *(const f32x4*)(x + base);
      f32x4 ov;
      #pragma unroll
      for (int i=0;i<4;++i) ov[i] = xv[i] + gm*a[i];
      *(f32x4*)(out + base) = ov;
    }
  }
}

extern "C" void kernel_launch(void* const* d_in, const int* in_sizes, int n_in,
                              void* d_out, int out_size, void* d_ws, size_t ws_size,
                              hipStream_t stream)
{
  const float* x     = (const float*)d_in[0];
  const float* Wf    = (const float*)d_in[1];
  const float* bf    = (const float*)d_in[2];
  const float* Wg    = (const float*)d_in[3];
  const float* bg    = (const float*)d_in[4];
  const float* Wh    = (const float*)d_in[5];
  const float* bh    = (const float*)d_in[6];
  const float* gamma = (const float*)d_in[7];
  float* out = (float*)d_out;

  short* fT   = (short*)d_ws;                       // [B][N][16] bf16
  short* gT   = fT + (size_t)BB*NN*CPj;             // [B][N][16] bf16
  short* hL   = gT + (size_t)BB*NN*CPj;             // [B][C][N]  bf16
  float* Mrow = (float*)(hL + (size_t)BB*CC*NN);    // [B][N]
  float* Zinv = Mrow + (size_t)BB*NN;               // [B][N]

  k_proj  <<<BB*64*4, 256, 0, stream>>>(x, Wf, bf, Wg, bg, Wh, bh, fT, gT, hL);
  k_stats <<<BB*64,   512, 0, stream>>>(fT, gT, Mrow, Zinv);
  k_attend<<<BB*64,   512, 0, stream>>>(x, fT, gT, hL, Mrow, Zinv, gamma, out);
}